// Round 1
// baseline (18951.549 us; speedup 1.0000x reference)
//
#include <hip/hip_runtime.h>

namespace {
constexpr int Sdim = 196;
constexpr int Ddim = 512;
constexpr int Cdim = 1006;
constexpr int CB = 16;    // classes per block
constexpr int EB = 128;   // output channels per block
constexpr int BK = 32;    // k-chunk for W staging
constexpr int NTHREADS = 256;

__device__ __forceinline__ float fast_exp(float x) {
    return __expf(x);
}

__device__ __forceinline__ float fast_tanh(float x) {
    // tanh(x) = 1 - 2/(exp(2x)+1); handles +-inf correctly (saturates to +-1)
    float e = __expf(2.0f * x);
    return 1.0f - 2.0f * __builtin_amdgcn_rcpf(e + 1.0f);
}

__global__ __launch_bounds__(NTHREADS) void semdec_kernel(
    const float* __restrict__ img,   // (2, S, D)
    const float* __restrict__ word,  // (C, D)
    const float* __restrict__ fw,    // (D, D)  [e][d]
    float* __restrict__ out)         // (2, C, D)
{
    __shared__ float ldsT[CB][Ddim + 1];   // tanh tile, +1 pad vs bank conflicts
    __shared__ float ldsW[EB][BK + 1];     // W chunk, +1 pad
    __shared__ float ldsImg[Ddim];         // img row for current s

    const int et = blockIdx.x;   // 0..3   e-tile
    const int ct = blockIdx.y;   // 0..62  c-tile
    const int b  = blockIdx.z;   // 0..1
    const int tid = threadIdx.x;

    const int e0 = et * EB;
    const int c0 = ct * CB;

    // micro-tile mapping: 2048 outputs / 256 threads = 8 per thread (2c x 4e)
    // e values are strided by 32 so LDS W reads cover all 32 banks.
    const int e_idx = tid & 31;   // thread's e: e_idx + 32*j, j=0..3
    const int c_idx = tid >> 5;   // thread's c: c_idx*2 + i, i=0..1
    const int cl = c_idx * 2;

    float l_sum[2][4];
    float a_sum[2][4];
    #pragma unroll
    for (int i = 0; i < 2; ++i)
        #pragma unroll
        for (int j = 0; j < 4; ++j) { l_sum[i][j] = 0.0f; a_sum[i][j] = 0.0f; }

    const float* imgB = img + (size_t)b * Sdim * Ddim;

    for (int s = 0; s < Sdim; ++s) {
        __syncthreads();  // previous iteration's readers of ldsImg/ldsT done
        // stage img row (512 floats)
        #pragma unroll
        for (int i = 0; i < Ddim / NTHREADS; ++i) {
            int d = i * NTHREADS + tid;
            ldsImg[d] = imgB[s * Ddim + d];
        }
        __syncthreads();
        // T[c][d] = tanh(img[d] * word[c0+c][d]) ; 16x512 = 32 iters/thread
        for (int i = 0; i < (CB * Ddim) / NTHREADS; ++i) {
            int idx = i * NTHREADS + tid;
            int c = idx >> 9;          // /512
            int d = idx & (Ddim - 1);
            int cg = c0 + c;
            if (cg > Cdim - 1) cg = Cdim - 1;  // clamp padded classes (stores guarded)
            ldsT[c][d] = fast_tanh(ldsImg[d] * word[(size_t)cg * Ddim + d]);
        }

        float feat[2][4];
        #pragma unroll
        for (int i = 0; i < 2; ++i)
            #pragma unroll
            for (int j = 0; j < 4; ++j) feat[i][j] = 0.0f;

        for (int kk = 0; kk < Ddim; kk += BK) {
            __syncthreads();  // prev chunk's readers done / T visible (1st iter)
            // stage W[e0..e0+128)[kk..kk+32)
            #pragma unroll
            for (int i = 0; i < (EB * BK) / NTHREADS; ++i) {
                int idx = i * NTHREADS + tid;
                int e = idx >> 5;      // /32
                int dd = idx & 31;
                ldsW[e][dd] = fw[(size_t)(e0 + e) * Ddim + kk + dd];
            }
            __syncthreads();
            #pragma unroll
            for (int k = 0; k < BK; ++k) {
                float t0 = ldsT[cl + 0][kk + k];   // broadcast reads (2 addrs/wave)
                float t1 = ldsT[cl + 1][kk + k];
                float w0 = ldsW[e_idx +  0][k];    // 32 distinct banks/wave
                float w1 = ldsW[e_idx + 32][k];
                float w2 = ldsW[e_idx + 64][k];
                float w3 = ldsW[e_idx + 96][k];
                feat[0][0] += t0 * w0; feat[0][1] += t0 * w1;
                feat[0][2] += t0 * w2; feat[0][3] += t0 * w3;
                feat[1][0] += t1 * w0; feat[1][1] += t1 * w1;
                feat[1][2] += t1 * w2; feat[1][3] += t1 * w3;
            }
        }

        // online softmax accumulation (no max-sub needed: |feat| <= ~8.2)
        #pragma unroll
        for (int j = 0; j < 4; ++j) {
            float iv = ldsImg[e0 + e_idx + 32 * j];
            #pragma unroll
            for (int i = 0; i < 2; ++i) {
                float ev = fast_exp(feat[i][j]);
                l_sum[i][j] += ev;
                a_sum[i][j] += iv * ev;
            }
        }
    }

    // out[b][c][e] = acc / l
    #pragma unroll
    for (int i = 0; i < 2; ++i) {
        int cg = c0 + cl + i;
        if (cg >= Cdim) continue;
        #pragma unroll
        for (int j = 0; j < 4; ++j) {
            int eg = e0 + e_idx + 32 * j;
            out[((size_t)b * Cdim + cg) * Ddim + eg] = a_sum[i][j] / l_sum[i][j];
        }
    }
}

} // namespace

extern "C" void kernel_launch(void* const* d_in, const int* in_sizes, int n_in,
                              void* d_out, int out_size, void* d_ws, size_t ws_size,
                              hipStream_t stream) {
    const float* img  = (const float*)d_in[0];   // imgFeaturemap (2,196,512)
    const float* word = (const float*)d_in[1];   // wordFeatures  (1006,512)
    const float* fw   = (const float*)d_in[2];   // fc3_w         (512,512)
    // d_in[3] = fc3_b: constant over the softmax axis (s) -> cancels exactly; unused.
    float* out = (float*)d_out;                  // (2,1006,512) fp32

    dim3 grid(Ddim / EB, (Cdim + CB - 1) / CB, 2);   // (4, 63, 2) = 504 blocks
    dim3 block(NTHREADS);
    hipLaunchKernelGGL(semdec_kernel, grid, block, 0, stream, img, word, fw, out);
}

// Round 2
// 423.170 us; speedup vs baseline: 44.7847x; 44.7847x over previous
//
#include <hip/hip_runtime.h>

using half8  = __attribute__((ext_vector_type(8))) _Float16;
using half4  = __attribute__((ext_vector_type(4))) _Float16;
using floatx4 = __attribute__((ext_vector_type(4))) float;

namespace {
constexpr int S = 196, D = 512, C = 1006, Cpad = 1024;
constexpr int CB = 64;      // block c-tile
constexpr int EBLK = 256;   // block e-tile
constexpr int BK = 64;      // k-chunk
constexpr int TPB = 512;    // 8 waves
constexpr int SCH = 4;      // s-chunks -> 49 s each = 24 pairs + 1 single
constexpr int SPC = 49;
constexpr int PAD = 8;                // halfs of row padding
constexpr int RS = BK + PAD;          // 72 halfs = 144 B row stride (16B aligned)

// ws layout (bytes)
constexpr size_t W16_BYTES = (size_t)D * D * 2;               // 512 KB
constexpr size_t LA_OFF    = W16_BYTES;
constexpr size_t L_BYTES   = (size_t)2 * Cpad * D * 4;        // 4 MB (atomic path l)
constexpr size_t SL_BYTES  = (size_t)SCH * 2 * Cpad * D * 4;  // 16 MB per (l or a) slice set
constexpr size_t SLICE_NEED = LA_OFF + 2 * SL_BYTES;          // ~33.5 MB

__device__ __forceinline__ float fast_tanh(float x) {
    float e = __expf(2.0f * x);                       // finite for |x| < ~40
    return 1.0f - 2.0f * __builtin_amdgcn_rcpf(e + 1.0f);
}

__global__ void prep_w16(const float* __restrict__ fw, _Float16* __restrict__ W16) {
    int i = (blockIdx.x * blockDim.x + threadIdx.x) * 4;   // 65536 threads * 4 = 262144
    floatx4 v = *(const floatx4*)&fw[i];
    half4 h;
    h[0] = (_Float16)v[0]; h[1] = (_Float16)v[1];
    h[2] = (_Float16)v[2]; h[3] = (_Float16)v[3];
    *(half4*)&W16[i] = h;
}

__global__ __launch_bounds__(TPB, 2) void semdec_mfma(
    const float* __restrict__ img, const float* __restrict__ word,
    const _Float16* __restrict__ W16,
    float* __restrict__ lbase, float* __restrict__ abase, int use_slice)
{
    __shared__ _Float16 Wc[EBLK * RS];     // 36864 B
    __shared__ _Float16 Tc[2 * CB * RS];   // 18432 B
    __shared__ float imgL[2][D];           // 4096 B

    const int ct = blockIdx.x;           // 0..15
    const int et = blockIdx.y & 1;       // 0..1
    const int b  = blockIdx.y >> 1;      // 0..1
    const int sc = blockIdx.z;           // 0..SCH-1

    const int tid  = threadIdx.x;
    const int lane = tid & 63;
    const int w    = tid >> 6;           // wave 0..7
    const int cw   = w >> 2;             // 0..1
    const int ew   = w & 3;              // 0..3
    const int l15  = lane & 15;
    const int quad = lane >> 4;

    const int c0 = ct * CB;
    const int e0 = et * EBLK;

    // softmax running sums, persist across s
    floatx4 lacc[2][4], aacc[2][4];
    #pragma unroll
    for (int ci = 0; ci < 2; ++ci)
        #pragma unroll
        for (int ej = 0; ej < 4; ++ej) {
            lacc[ci][ej] = (floatx4){0.f, 0.f, 0.f, 0.f};
            aacc[ci][ej] = (floatx4){0.f, 0.f, 0.f, 0.f};
        }

    const float* imgB = img + (size_t)b * S * D;
    const int s_base = sc * SPC;

    for (int pr = 0; pr < 25; ++pr) {
        const int s0 = s_base + pr * 2;
        const bool s1v = (pr < 24);
        const int s1 = s1v ? s0 + 1 : s0;

        __syncthreads();  // prior accum/MFMA readers of imgL/Tc/Wc done
        imgL[0][tid] = imgB[(size_t)s0 * D + tid];
        imgL[1][tid] = imgB[(size_t)s1 * D + tid];

        floatx4 acc[2][2][4];   // [s][ci][ej]
        #pragma unroll
        for (int si = 0; si < 2; ++si)
            #pragma unroll
            for (int ci = 0; ci < 2; ++ci)
                #pragma unroll
                for (int ej = 0; ej < 4; ++ej)
                    acc[si][ci][ej] = (floatx4){0.f, 0.f, 0.f, 0.f};

        for (int kk = 0; kk < D; kk += BK) {
            __syncthreads();  // prev chunk MFMA readers done / img staged (kk=0)
            // --- W chunk: 256 rows x 64 halfs = 2048 half8-segs, 4/thread
            #pragma unroll
            for (int it = 0; it < 4; ++it) {
                int sid = it * TPB + tid;
                int row = sid >> 3, seg = sid & 7;
                half8 v = *(const half8*)&W16[(size_t)(e0 + row) * D + kk + seg * 8];
                *(half8*)&Wc[row * RS + seg * 8] = v;
            }
            // --- T chunk: 2s x 64c x 64d = 1024 half8-segs, 2/thread
            #pragma unroll
            for (int it = 0; it < 2; ++it) {
                int sid = it * TPB + tid;
                int si = sid >> 9, rem = sid & 511;
                int ci = rem >> 3, dseg = rem & 7;
                int cg = c0 + ci; if (cg > C - 1) cg = C - 1;   // clamp pad rows
                const float* wp = &word[(size_t)cg * D + kk + dseg * 8];
                floatx4 w0 = *(const floatx4*)wp;
                floatx4 w1 = *(const floatx4*)(wp + 4);
                const float* ip = &imgL[si][kk + dseg * 8];
                floatx4 i0 = *(const floatx4*)ip;
                floatx4 i1 = *(const floatx4*)(ip + 4);
                half8 t;
                t[0] = (_Float16)fast_tanh(i0[0] * w0[0]);
                t[1] = (_Float16)fast_tanh(i0[1] * w0[1]);
                t[2] = (_Float16)fast_tanh(i0[2] * w0[2]);
                t[3] = (_Float16)fast_tanh(i0[3] * w0[3]);
                t[4] = (_Float16)fast_tanh(i1[0] * w1[0]);
                t[5] = (_Float16)fast_tanh(i1[1] * w1[1]);
                t[6] = (_Float16)fast_tanh(i1[2] * w1[2]);
                t[7] = (_Float16)fast_tanh(i1[3] * w1[3]);
                *(half8*)&Tc[(si * CB + ci) * RS + dseg * 8] = t;
            }
            __syncthreads();
            // --- MFMA: 2 k-steps of 32
            #pragma unroll
            for (int k2 = 0; k2 < BK; k2 += 32) {
                half8 af[2][2], bf[4];
                #pragma unroll
                for (int si = 0; si < 2; ++si)
                    #pragma unroll
                    for (int ci = 0; ci < 2; ++ci)
                        af[si][ci] = *(const half8*)&Tc[(si * CB + cw * 32 + ci * 16 + l15) * RS + k2 + quad * 8];
                #pragma unroll
                for (int ej = 0; ej < 4; ++ej)
                    bf[ej] = *(const half8*)&Wc[(ew * 64 + ej * 16 + l15) * RS + k2 + quad * 8];
                #pragma unroll
                for (int si = 0; si < 2; ++si)
                    #pragma unroll
                    for (int ci = 0; ci < 2; ++ci)
                        #pragma unroll
                        for (int ej = 0; ej < 4; ++ej)
                            acc[si][ci][ej] = __builtin_amdgcn_mfma_f32_16x16x32_f16(
                                af[si][ci], bf[ej], acc[si][ci][ej], 0, 0, 0);
            }
        }
        // --- online softmax accumulate (bias cancels in softmax; no max-sub: |feat|<~12)
        #pragma unroll
        for (int si = 0; si < 2; ++si) {
            if (si == 1 && !s1v) break;
            #pragma unroll
            for (int ej = 0; ej < 4; ++ej) {
                float ie = imgL[si][e0 + ew * 64 + ej * 16 + l15];
                #pragma unroll
                for (int ci = 0; ci < 2; ++ci)
                    #pragma unroll
                    for (int r = 0; r < 4; ++r) {
                        float ev = __expf(acc[si][ci][ej][r]);
                        lacc[ci][ej][r] += ev;
                        aacc[ci][ej][r] += ie * ev;
                    }
            }
        }
    }

    // --- writeout
    if (use_slice) {
        float* lsl = lbase + (size_t)sc * 2 * Cpad * D;
        float* asl = abase + (size_t)sc * 2 * Cpad * D;
        #pragma unroll
        for (int ci = 0; ci < 2; ++ci)
            #pragma unroll
            for (int r = 0; r < 4; ++r) {
                int cg = c0 + cw * 32 + ci * 16 + quad * 4 + r;
                #pragma unroll
                for (int ej = 0; ej < 4; ++ej) {
                    int eg = e0 + ew * 64 + ej * 16 + l15;
                    size_t o = ((size_t)b * Cpad + cg) * D + eg;
                    lsl[o] = lacc[ci][ej][r];
                    asl[o] = aacc[ci][ej][r];
                }
            }
    } else {
        #pragma unroll
        for (int ci = 0; ci < 2; ++ci)
            #pragma unroll
            for (int r = 0; r < 4; ++r) {
                int cg = c0 + cw * 32 + ci * 16 + quad * 4 + r;
                #pragma unroll
                for (int ej = 0; ej < 4; ++ej) {
                    int eg = e0 + ew * 64 + ej * 16 + l15;
                    atomicAdd(&lbase[((size_t)b * Cpad + cg) * D + eg], lacc[ci][ej][r]);
                    if (cg < C)
                        atomicAdd(&abase[((size_t)b * C + cg) * D + eg], aacc[ci][ej][r]);
                }
            }
    }
}

__global__ void finalize_k(const float* __restrict__ lbase, const float* __restrict__ abase,
                           float* __restrict__ out, int use_slice) {
    int o = blockIdx.x * blockDim.x + threadIdx.x;
    if (o >= 2 * C * D) return;
    int b = o / (C * D);
    int rem = o - b * (C * D);
    int c = rem >> 9;
    int e = rem & (D - 1);
    size_t p = ((size_t)b * Cpad + c) * D + e;
    if (use_slice) {
        float l = 0.f, a = 0.f;
        #pragma unroll
        for (int scn = 0; scn < SCH; ++scn) {
            l += lbase[(size_t)scn * 2 * Cpad * D + p];
            a += abase[(size_t)scn * 2 * Cpad * D + p];
        }
        out[o] = a / l;
    } else {
        out[o] = out[o] / lbase[p];
    }
}

} // namespace

extern "C" void kernel_launch(void* const* d_in, const int* in_sizes, int n_in,
                              void* d_out, int out_size, void* d_ws, size_t ws_size,
                              hipStream_t stream) {
    const float* img  = (const float*)d_in[0];
    const float* word = (const float*)d_in[1];
    const float* fw   = (const float*)d_in[2];
    // d_in[3] = fc3_b: constant over softmax axis s -> cancels exactly.
    float* out = (float*)d_out;
    char* ws = (char*)d_ws;

    _Float16* W16 = (_Float16*)ws;
    const int use_slice = (ws_size >= SLICE_NEED) ? 1 : 0;

    hipLaunchKernelGGL(prep_w16, dim3(256), dim3(256), 0, stream, fw, W16);

    float *lbase, *abase;
    if (use_slice) {
        lbase = (float*)(ws + LA_OFF);
        abase = (float*)(ws + LA_OFF + SL_BYTES);
        // all slice cells are written by the grid; no memset needed
    } else {
        lbase = (float*)(ws + LA_OFF);
        abase = out;
        hipMemsetAsync(lbase, 0, L_BYTES, stream);
        hipMemsetAsync(out, 0, (size_t)2 * C * D * 4, stream);
    }

    hipLaunchKernelGGL(semdec_mfma, dim3(16, 4, SCH), dim3(TPB), 0, stream,
                       img, word, W16, lbase, abase, use_slice);

    hipLaunchKernelGGL(finalize_k, dim3((2 * C * D + 255) / 256), dim3(256), 0, stream,
                       lbase, abase, out, use_slice);
}

// Round 3
// 387.278 us; speedup vs baseline: 48.9353x; 1.0927x over previous
//
#include <hip/hip_runtime.h>

using half8   = __attribute__((ext_vector_type(8))) _Float16;
using half4   = __attribute__((ext_vector_type(4))) _Float16;
using floatx4 = __attribute__((ext_vector_type(4))) float;

namespace {
constexpr int S = 196, D = 512, C = 1006, Cpad = 1024;
constexpr int CB = 32;      // block c-tile
constexpr int EBLK = 256;   // block e-tile
constexpr int BK = 64;      // k-chunk
constexpr int TPB = 256;    // 4 waves -> 2 blocks/CU for cross-block overlap
constexpr int SCH = 4;      // s-chunks (49 s each: 24 pairs + 1 single)
constexpr int SPC = 49;
constexpr int RS = 64;      // row stride in halfs; bank safety via XOR swizzle

// ws layout (bytes)
constexpr size_t W16_BYTES = (size_t)D * D * 2;               // 512 KB
constexpr size_t LA_OFF    = W16_BYTES;
constexpr size_t L_BYTES   = (size_t)2 * Cpad * D * 4;        // 4 MB (atomic path l)
constexpr size_t SL_BYTES  = (size_t)SCH * 2 * Cpad * D * 4;  // 16 MB per slice set
constexpr size_t SLICE_NEED = LA_OFF + 2 * SL_BYTES;          // ~33.5 MB

// swizzled LDS offset: row stride 64 halfs, 16B segment XOR'd by row&7
__device__ __forceinline__ int sw_off(int row, int seg) {
    return row * RS + ((seg ^ (row & 7)) << 3);
}

__device__ __forceinline__ float fast_tanh(float x) {
    // tanh(x) = 1 - 2/(exp2(x*2/ln2)+1); saturates correctly for large |x|
    float e = __builtin_amdgcn_exp2f(2.885390082f * x);
    return 1.0f - 2.0f * __builtin_amdgcn_rcpf(e + 1.0f);
}

__global__ void prep_w16(const float* __restrict__ fw, _Float16* __restrict__ W16) {
    int i = (blockIdx.x * blockDim.x + threadIdx.x) * 4;
    floatx4 v = *(const floatx4*)&fw[i];
    half4 h;
    h[0] = (_Float16)v[0]; h[1] = (_Float16)v[1];
    h[2] = (_Float16)v[2]; h[3] = (_Float16)v[3];
    *(half4*)&W16[i] = h;
}

__global__ __launch_bounds__(TPB, 2) void semdec_mfma(
    const float* __restrict__ img, const float* __restrict__ word,
    const _Float16* __restrict__ W16,
    float* __restrict__ lbase, float* __restrict__ abase, int use_slice)
{
    __shared__ _Float16 Wc[EBLK * RS];     // 32768 B
    __shared__ _Float16 Tc[2 * CB * RS];   // 8192 B
    __shared__ float imgL[2][D];           // 4096 B

    const int ct = blockIdx.x;           // 0..31
    const int et = blockIdx.y & 1;       // 0..1
    const int b  = blockIdx.y >> 1;      // 0..1
    const int sc = blockIdx.z;           // 0..SCH-1

    const int tid  = threadIdx.x;
    const int lane = tid & 63;
    const int ew   = tid >> 6;           // wave 0..3 = e-slot
    const int l15  = lane & 15;
    const int quad = lane >> 4;

    const int c0 = ct * CB;
    const int e0 = et * EBLK;

    floatx4 lacc[2][4], aacc[2][4];
    #pragma unroll
    for (int ci = 0; ci < 2; ++ci)
        #pragma unroll
        for (int ej = 0; ej < 4; ++ej) {
            lacc[ci][ej] = (floatx4){0.f, 0.f, 0.f, 0.f};
            aacc[ci][ej] = (floatx4){0.f, 0.f, 0.f, 0.f};
        }

    const float* imgB = img + (size_t)b * S * D;
    const int s_base = sc * SPC;

    for (int pr = 0; pr < 25; ++pr) {
        const int s0 = s_base + pr * 2;
        const bool s1v = (pr < 24);
        const int s1 = s1v ? s0 + 1 : s0;

        __syncthreads();  // prior readers of imgL/Tc/Wc done
        imgL[0][tid]       = imgB[(size_t)s0 * D + tid];
        imgL[0][tid + 256] = imgB[(size_t)s0 * D + tid + 256];
        imgL[1][tid]       = imgB[(size_t)s1 * D + tid];
        imgL[1][tid + 256] = imgB[(size_t)s1 * D + tid + 256];

        floatx4 acc[2][2][4];   // [s][ci][ej]
        #pragma unroll
        for (int si = 0; si < 2; ++si)
            #pragma unroll
            for (int ci = 0; ci < 2; ++ci)
                #pragma unroll
                for (int ej = 0; ej < 4; ++ej)
                    acc[si][ci][ej] = (floatx4){0.f, 0.f, 0.f, 0.f};

        for (int kk = 0; kk < D; kk += BK) {
            __syncthreads();  // prev chunk MFMA readers done / img staged (kk=0)
            // --- W chunk: 256 rows x 8 segs = 2048 half8-segs, 8/thread
            #pragma unroll
            for (int it = 0; it < 8; ++it) {
                int sid = it * TPB + tid;
                int row = sid >> 3, seg = sid & 7;
                half8 v = *(const half8*)&W16[(size_t)(e0 + row) * D + kk + seg * 8];
                *(half8*)&Wc[sw_off(row, seg)] = v;
            }
            // --- T chunk: 2s x 32c x 8 segs = 512 half8-segs, 2/thread
            #pragma unroll
            for (int it = 0; it < 2; ++it) {
                int sid = it * TPB + tid;
                int si = sid >> 8, rem = sid & 255;
                int ci32 = rem >> 3, dseg = rem & 7;
                int cg = c0 + ci32; if (cg > C - 1) cg = C - 1;  // clamp pad rows
                const float* wp = &word[(size_t)cg * D + kk + dseg * 8];
                floatx4 w0 = *(const floatx4*)wp;
                floatx4 w1 = *(const floatx4*)(wp + 4);
                const float* ip = &imgL[si][kk + dseg * 8];
                floatx4 i0 = *(const floatx4*)ip;
                floatx4 i1 = *(const floatx4*)(ip + 4);
                half8 t;
                t[0] = (_Float16)fast_tanh(i0[0] * w0[0]);
                t[1] = (_Float16)fast_tanh(i0[1] * w0[1]);
                t[2] = (_Float16)fast_tanh(i0[2] * w0[2]);
                t[3] = (_Float16)fast_tanh(i0[3] * w0[3]);
                t[4] = (_Float16)fast_tanh(i1[0] * w1[0]);
                t[5] = (_Float16)fast_tanh(i1[1] * w1[1]);
                t[6] = (_Float16)fast_tanh(i1[2] * w1[2]);
                t[7] = (_Float16)fast_tanh(i1[3] * w1[3]);
                *(half8*)&Tc[sw_off(si * CB + ci32, dseg)] = t;
            }
            __syncthreads();
            // --- MFMA: 2 k-steps of 32
            #pragma unroll
            for (int k2 = 0; k2 < BK; k2 += 32) {
                const int jb = (k2 >> 3) + quad;   // 16B-segment index for this lane
                half8 af[2][2], bf[4];
                #pragma unroll
                for (int si = 0; si < 2; ++si)
                    #pragma unroll
                    for (int ci = 0; ci < 2; ++ci)
                        af[si][ci] = *(const half8*)&Tc[sw_off(si * CB + ci * 16 + l15, jb)];
                #pragma unroll
                for (int ej = 0; ej < 4; ++ej)
                    bf[ej] = *(const half8*)&Wc[sw_off(ew * 64 + ej * 16 + l15, jb)];
                #pragma unroll
                for (int si = 0; si < 2; ++si)
                    #pragma unroll
                    for (int ci = 0; ci < 2; ++ci)
                        #pragma unroll
                        for (int ej = 0; ej < 4; ++ej)
                            acc[si][ci][ej] = __builtin_amdgcn_mfma_f32_16x16x32_f16(
                                af[si][ci], bf[ej], acc[si][ci][ej], 0, 0, 0);
            }
        }
        // --- online softmax accumulate (bias cancels; |feat| small, no max-sub)
        #pragma unroll
        for (int si = 0; si < 2; ++si) {
            if (si == 1 && !s1v) break;
            #pragma unroll
            for (int ej = 0; ej < 4; ++ej) {
                float ie = imgL[si][e0 + ew * 64 + ej * 16 + l15];
                #pragma unroll
                for (int ci = 0; ci < 2; ++ci)
                    #pragma unroll
                    for (int r = 0; r < 4; ++r) {
                        float ev = __expf(acc[si][ci][ej][r]);
                        lacc[ci][ej][r] += ev;
                        aacc[ci][ej][r] += ie * ev;
                    }
            }
        }
    }

    // --- writeout
    if (use_slice) {
        float* lsl = lbase + (size_t)sc * 2 * Cpad * D;
        float* asl = abase + (size_t)sc * 2 * Cpad * D;
        #pragma unroll
        for (int ci = 0; ci < 2; ++ci)
            #pragma unroll
            for (int r = 0; r < 4; ++r) {
                int cg = c0 + ci * 16 + quad * 4 + r;
                #pragma unroll
                for (int ej = 0; ej < 4; ++ej) {
                    int eg = e0 + ew * 64 + ej * 16 + l15;
                    size_t o = ((size_t)b * Cpad + cg) * D + eg;
                    lsl[o] = lacc[ci][ej][r];
                    asl[o] = aacc[ci][ej][r];
                }
            }
    } else {
        #pragma unroll
        for (int ci = 0; ci < 2; ++ci)
            #pragma unroll
            for (int r = 0; r < 4; ++r) {
                int cg = c0 + ci * 16 + quad * 4 + r;
                #pragma unroll
                for (int ej = 0; ej < 4; ++ej) {
                    int eg = e0 + ew * 64 + ej * 16 + l15;
                    atomicAdd(&lbase[((size_t)b * Cpad + cg) * D + eg], lacc[ci][ej][r]);
                    if (cg < C)
                        atomicAdd(&abase[((size_t)b * C + cg) * D + eg], aacc[ci][ej][r]);
                }
            }
    }
}

__global__ void finalize_k(const float* __restrict__ lbase, const float* __restrict__ abase,
                           float* __restrict__ out, int use_slice) {
    int o = blockIdx.x * blockDim.x + threadIdx.x;
    if (o >= 2 * C * D) return;
    int b = o / (C * D);
    int rem = o - b * (C * D);
    int c = rem >> 9;
    int e = rem & (D - 1);
    size_t p = ((size_t)b * Cpad + c) * D + e;
    if (use_slice) {
        float l = 0.f, a = 0.f;
        #pragma unroll
        for (int scn = 0; scn < SCH; ++scn) {
            l += lbase[(size_t)scn * 2 * Cpad * D + p];
            a += abase[(size_t)scn * 2 * Cpad * D + p];
        }
        out[o] = a / l;
    } else {
        out[o] = out[o] / lbase[p];
    }
}

} // namespace

extern "C" void kernel_launch(void* const* d_in, const int* in_sizes, int n_in,
                              void* d_out, int out_size, void* d_ws, size_t ws_size,
                              hipStream_t stream) {
    const float* img  = (const float*)d_in[0];
    const float* word = (const float*)d_in[1];
    const float* fw   = (const float*)d_in[2];
    // d_in[3] = fc3_b: constant over softmax axis s -> cancels exactly.
    float* out = (float*)d_out;
    char* ws = (char*)d_ws;

    _Float16* W16 = (_Float16*)ws;
    const int use_slice = (ws_size >= SLICE_NEED) ? 1 : 0;

    hipLaunchKernelGGL(prep_w16, dim3(256), dim3(256), 0, stream, fw, W16);

    float *lbase, *abase;
    if (use_slice) {
        lbase = (float*)(ws + LA_OFF);
        abase = (float*)(ws + LA_OFF + SL_BYTES);
    } else {
        lbase = (float*)(ws + LA_OFF);
        abase = out;
        hipMemsetAsync(lbase, 0, L_BYTES, stream);
        hipMemsetAsync(out, 0, (size_t)2 * C * D * 4, stream);
    }

    hipLaunchKernelGGL(semdec_mfma, dim3(32, 4, SCH), dim3(TPB), 0, stream,
                       img, word, W16, lbase, abase, use_slice);

    hipLaunchKernelGGL(finalize_k, dim3((2 * C * D + 255) / 256), dim3(256), 0, stream,
                       lbase, abase, out, use_slice);
}

// Round 4
// 374.674 us; speedup vs baseline: 50.5814x; 1.0336x over previous
//
#include <hip/hip_runtime.h>

using half8   = __attribute__((ext_vector_type(8))) _Float16;
using floatx4 = __attribute__((ext_vector_type(4))) float;

namespace {
constexpr int S = 196, D = 512, C = 1006, Cpad = 1024;
constexpr int CB = 16;      // block c-tile (16 -> sums = 32 VGPR)
constexpr int EBLK = 256;   // block e-tile (keeps tanh duplication at x2)
constexpr int BK = 64;      // k-chunk
constexpr int TPB = 256;    // 4 waves; 3 blocks/CU targeted (reg-limited)
constexpr int SCH = 3;      // s-chunks: 66, 66, 64 -> grid 768 = 3 blocks/CU exactly
constexpr int RS = 64;      // LDS row stride (halfs); banks handled by XOR swizzle
constexpr float KTANH = 2.885390082f;    // 2/ln2, folded into img staging
constexpr float INVK  = 0.34657359028f;  // ln2/2, to recover raw img for pooling

// ws layout (bytes)
constexpr size_t W16_BYTES = (size_t)D * D * 2;               // 512 KB pre-swizzled W
constexpr size_t LA_OFF    = W16_BYTES;
constexpr size_t SLICE_ELEMS = (size_t)2 * Cpad * D;          // per-slice l or a
constexpr size_t SL_BYTES  = (size_t)SCH * SLICE_ELEMS * 4;   // 12 MB per set
constexpr size_t SLICE_NEED = LA_OFF + 2 * SL_BYTES;          // ~24.5 MB
constexpr size_t L_BYTES   = SLICE_ELEMS * 4;                 // atomic-path l

// swizzled LDS offset (halfs): row stride 64, 16B-seg XOR'd by row&7 (conflict-free, r3-verified)
__device__ __forceinline__ int sw_off(int row, int seg) {
    return row * RS + ((seg ^ (row & 7)) << 3);
}

__device__ __forceinline__ void gload16(const _Float16* g, _Float16* l) {
    // async global->LDS, 16B/lane; LDS dest = wave-uniform base + lane*16
    __builtin_amdgcn_global_load_lds(
        (const __attribute__((address_space(1))) unsigned int*)g,
        (__attribute__((address_space(3))) unsigned int*)l, 16, 0, 0);
}

__device__ __forceinline__ _Float16 tanh_ps(float y) {
    // y = (2/ln2)*x ; tanh(x) = 1 - 2/(exp2(y)+1), saturates correctly
    float e = __builtin_amdgcn_exp2f(y);
    return (_Float16)(1.0f - 2.0f * __builtin_amdgcn_rcpf(e + 1.0f));
}

// Pre-swizzle fc3_w into the per-chunk LDS image layout:
// chunk kki (0..7) | row r (0..511) | seg j (0..7, XOR r&7) -> exact Wc image
__global__ void prep_w16sw(const float* __restrict__ fw, _Float16* __restrict__ W16sw) {
    int id = blockIdx.x * blockDim.x + threadIdx.x;    // 32768 = 8*512*8 segs
    int kki = id >> 12;
    int r   = (id >> 3) & 511;
    int j   = id & 7;
    const float* src = fw + (size_t)r * D + kki * 64 + j * 8;
    floatx4 v0 = *(const floatx4*)src;
    floatx4 v1 = *(const floatx4*)(src + 4);
    half8 h;
    h[0] = (_Float16)v0[0]; h[1] = (_Float16)v0[1];
    h[2] = (_Float16)v0[2]; h[3] = (_Float16)v0[3];
    h[4] = (_Float16)v1[0]; h[5] = (_Float16)v1[1];
    h[6] = (_Float16)v1[2]; h[7] = (_Float16)v1[3];
    *(half8*)&W16sw[((size_t)kki << 15) + r * RS + ((j ^ (r & 7)) << 3)] = h;
}

__global__ __launch_bounds__(TPB, 3) void semdec_mfma(
    const float* __restrict__ img, const float* __restrict__ word,
    const _Float16* __restrict__ W16sw,
    float* __restrict__ lbase, float* __restrict__ abase, int use_slice)
{
    __shared__ __align__(16) _Float16 Wc[EBLK * RS];   // 32 KB
    __shared__ __align__(16) _Float16 Tc[4 * CB * RS]; // 8 KB (4 s x 16 c x 64 k)
    __shared__ __align__(16) float imgS[4][D];         // 8 KB, pre-scaled by 2/ln2
    // total 48 KB -> 3 blocks/CU LDS-wise

    const int ct = blockIdx.x;           // 0..63
    const int et = blockIdx.y & 1;       // 0..1
    const int b  = blockIdx.y >> 1;      // 0..1
    const int sc = blockIdx.z;           // 0..2

    const int tid  = threadIdx.x;
    const int lane = tid & 63;
    const int ew   = tid >> 6;           // wave 0..3 = 64-wide e-slot
    const int l15  = lane & 15;
    const int quad = lane >> 4;

    const int c0 = ct * CB;
    const int e0 = et * EBLK;

    floatx4 lacc[4], aacc[4];            // softmax sums: 32 VGPR
    #pragma unroll
    for (int ej = 0; ej < 4; ++ej) {
        lacc[ej] = (floatx4){0.f, 0.f, 0.f, 0.f};
        aacc[ej] = (floatx4){0.f, 0.f, 0.f, 0.f};
    }

    const float* imgB = img + (size_t)b * S * D;
    const int s_base = sc * 66;                       // 0, 66, 132
    const int npass = (sc < 2) ? 17 : 16;             // 16x4s (+1x2s for sc<2)

    for (int pr = 0; pr < npass; ++pr) {
        const int s0 = s_base + pr * 4;
        const int slim = (pr == 16) ? 2 : 4;          // tail pass covers 2 s

        __syncthreads();  // prior pass readers of imgS/Tc/Wc done
        // stage 4 pre-scaled img rows (tail si 2,3 read valid in-range rows, unused)
        #pragma unroll
        for (int it = 0; it < 2; ++it) {
            int sid = it * TPB + tid;
            int si = sid >> 7, pos = (sid & 127) << 2;
            floatx4 v = *(const floatx4*)&imgB[(size_t)(s0 + si) * D + pos];
            floatx4 sv = {v[0] * KTANH, v[1] * KTANH, v[2] * KTANH, v[3] * KTANH};
            *(floatx4*)&imgS[si][pos] = sv;
        }

        floatx4 acc[4][4];   // [si][ej] : 64 AGPR
        #pragma unroll
        for (int si = 0; si < 4; ++si)
            #pragma unroll
            for (int ej = 0; ej < 4; ++ej)
                acc[si][ej] = (floatx4){0.f, 0.f, 0.f, 0.f};

        for (int kk = 0; kk < D; kk += BK) {
            const int kki = kk >> 6;
            __syncthreads();  // prev chunk frag readers done / imgS staged (kk=0)
            // --- W chunk: async DMA of pre-swizzled image, 8 x 1KB per wave
            {
                const _Float16* wg = W16sw + ((size_t)kki << 15) + ((size_t)e0 << 6);
                #pragma unroll
                for (int it = 0; it < 8; ++it) {
                    int o = ((ew * 8 + it) << 9) + (lane << 3);
                    gload16(wg + o, &Wc[o]);
                }
            }
            // --- T chunk: 4s x 16c x 8 segs = 512 half8, 2/thread
            #pragma unroll
            for (int it = 0; it < 2; ++it) {
                int sid = it * TPB + tid;
                int si = sid >> 7, rem = sid & 127;
                int ci = rem >> 3, seg = rem & 7;
                int cg = c0 + ci; if (cg > C - 1) cg = C - 1;   // clamp pad rows
                const float* wp = &word[(size_t)cg * D + kk + seg * 8];
                floatx4 w0 = *(const floatx4*)wp;
                floatx4 w1 = *(const floatx4*)(wp + 4);
                const float* ip = &imgS[si][kk + seg * 8];
                floatx4 i0 = *(const floatx4*)ip;
                floatx4 i1 = *(const floatx4*)(ip + 4);
                half8 t;
                t[0] = tanh_ps(i0[0] * w0[0]);
                t[1] = tanh_ps(i0[1] * w0[1]);
                t[2] = tanh_ps(i0[2] * w0[2]);
                t[3] = tanh_ps(i0[3] * w0[3]);
                t[4] = tanh_ps(i1[0] * w1[0]);
                t[5] = tanh_ps(i1[1] * w1[1]);
                t[6] = tanh_ps(i1[2] * w1[2]);
                t[7] = tanh_ps(i1[3] * w1[3]);
                *(half8*)&Tc[sw_off(si * CB + ci, seg)] = t;
            }
            __syncthreads();  // drains vmcnt (async W) + lgkm (T writes)
            // --- MFMA: 2 k-steps of 32; 8 frag reads -> 16 MFMA
            #pragma unroll
            for (int k2 = 0; k2 < 2; ++k2) {
                const int jb = (k2 << 2) + quad;
                half8 bf[4], af[4];
                #pragma unroll
                for (int ej = 0; ej < 4; ++ej)
                    bf[ej] = *(const half8*)&Wc[sw_off(ew * 64 + ej * 16 + l15, jb)];
                #pragma unroll
                for (int si = 0; si < 4; ++si)
                    af[si] = *(const half8*)&Tc[sw_off(si * CB + l15, jb)];
                #pragma unroll
                for (int si = 0; si < 4; ++si)
                    #pragma unroll
                    for (int ej = 0; ej < 4; ++ej)
                        acc[si][ej] = __builtin_amdgcn_mfma_f32_16x16x32_f16(
                            af[si], bf[ej], acc[si][ej], 0, 0, 0);
            }
        }
        // --- online softmax accumulate (bias cancels; |feat| < ~35, no max-sub)
        #pragma unroll
        for (int si = 0; si < 4; ++si) {
            if (si >= slim) break;
            #pragma unroll
            for (int ej = 0; ej < 4; ++ej) {
                float ie = imgS[si][e0 + ew * 64 + ej * 16 + l15] * INVK;
                #pragma unroll
                for (int r = 0; r < 4; ++r) {
                    float ev = __builtin_amdgcn_exp2f(acc[si][ej][r] * 1.44269504f);
                    lacc[ej][r] += ev;
                    aacc[ej][r] += ie * ev;
                }
            }
        }
    }

    // --- writeout (C/D layout: col=lane&15 -> e, row=quad*4+r -> c)
    if (use_slice) {
        float* lsl = lbase + (size_t)sc * SLICE_ELEMS;
        float* asl = abase + (size_t)sc * SLICE_ELEMS;
        #pragma unroll
        for (int r = 0; r < 4; ++r) {
            int cg = c0 + quad * 4 + r;
            #pragma unroll
            for (int ej = 0; ej < 4; ++ej) {
                int eg = e0 + ew * 64 + ej * 16 + l15;
                size_t o = ((size_t)b * Cpad + cg) * D + eg;
                lsl[o] = lacc[ej][r];
                asl[o] = aacc[ej][r];
            }
        }
    } else {
        #pragma unroll
        for (int r = 0; r < 4; ++r) {
            int cg = c0 + quad * 4 + r;
            #pragma unroll
            for (int ej = 0; ej < 4; ++ej) {
                int eg = e0 + ew * 64 + ej * 16 + l15;
                atomicAdd(&lbase[((size_t)b * Cpad + cg) * D + eg], lacc[ej][r]);
                if (cg < C)
                    atomicAdd(&abase[((size_t)b * C + cg) * D + eg], aacc[ej][r]);
            }
        }
    }
}

__global__ void finalize_k(const float* __restrict__ lbase, const float* __restrict__ abase,
                           float* __restrict__ out, int use_slice) {
    int o = blockIdx.x * blockDim.x + threadIdx.x;
    if (o >= 2 * C * D) return;
    int b = o / (C * D);
    int rem = o - b * (C * D);
    int c = rem >> 9;
    int e = rem & (D - 1);
    size_t p = ((size_t)b * Cpad + c) * D + e;
    if (use_slice) {
        float l = 0.f, a = 0.f;
        #pragma unroll
        for (int scn = 0; scn < SCH; ++scn) {
            l += lbase[(size_t)scn * SLICE_ELEMS + p];
            a += abase[(size_t)scn * SLICE_ELEMS + p];
        }
        out[o] = a / l;
    } else {
        out[o] = out[o] / lbase[p];
    }
}

} // namespace

extern "C" void kernel_launch(void* const* d_in, const int* in_sizes, int n_in,
                              void* d_out, int out_size, void* d_ws, size_t ws_size,
                              hipStream_t stream) {
    const float* img  = (const float*)d_in[0];
    const float* word = (const float*)d_in[1];
    const float* fw   = (const float*)d_in[2];
    // d_in[3] = fc3_b: constant over softmax axis s -> cancels exactly.
    float* out = (float*)d_out;
    char* ws = (char*)d_ws;

    _Float16* W16sw = (_Float16*)ws;
    const int use_slice = (ws_size >= SLICE_NEED) ? 1 : 0;

    hipLaunchKernelGGL(prep_w16sw, dim3(128), dim3(256), 0, stream, fw, W16sw);

    float *lbase, *abase;
    if (use_slice) {
        lbase = (float*)(ws + LA_OFF);
        abase = (float*)(ws + LA_OFF + SL_BYTES);
    } else {
        lbase = (float*)(ws + LA_OFF);
        abase = out;
        hipMemsetAsync(lbase, 0, L_BYTES, stream);
        hipMemsetAsync(out, 0, (size_t)2 * C * D * 4, stream);
    }

    hipLaunchKernelGGL(semdec_mfma, dim3(64, 4, SCH), dim3(TPB), 0, stream,
                       img, word, W16sw, lbase, abase, use_slice);

    hipLaunchKernelGGL(finalize_k, dim3((2 * C * D + 255) / 256), dim3(256), 0, stream,
                       lbase, abase, out, use_slice);
}